// Round 11
// baseline (466.399 us; speedup 1.0000x reference)
//
#include <hip/hip_runtime.h>

#define BN_EPS 1e-5f

typedef unsigned short ushort_t;
typedef __attribute__((ext_vector_type(8))) short bf16x8;
typedef __attribute__((ext_vector_type(16))) float f32x16;

// round-to-nearest-even fp32 -> bf16 (finite inputs)
__device__ __forceinline__ ushort_t bf16rne(float f) {
    unsigned int u = __float_as_uint(f);
    unsigned int r = (u + 0x7FFFu + ((u >> 16) & 1u)) >> 16;
    return (ushort_t)r;
}
__device__ __forceinline__ unsigned int pack2(float a, float b) {
    return (unsigned int)bf16rne(a) | ((unsigned int)bf16rne(b) << 16);
}
__device__ __forceinline__ void cvt2(unsigned int u, float& lo, float& hi) {
    lo = __uint_as_float(u << 16);
    hi = __uint_as_float(u & 0xFFFF0000u);
}
__device__ __forceinline__ bf16x8 as_bf16x8(uint4 u) {
    union { uint4 u; bf16x8 v; } c; c.u = u; return c.v;
}

// ---------------- CSR build: locality-aware 2-pass counting sort ----------------
// binned entry packs src (bits 0-16) | local-dst (bits 24-31).

#define BIN_CHUNK 4096

__global__ __launch_bounds__(256) void k_binhist(const int* __restrict__ dst, int E, int NB,
                                                 int* __restrict__ bucket_counts) {
    __shared__ int hist[512];
    for (int i = threadIdx.x; i < NB; i += 256) hist[i] = 0;
    __syncthreads();
    int base = blockIdx.x * BIN_CHUNK;
    int end = min(E, base + BIN_CHUNK);
    for (int e = base + threadIdx.x; e < end; e += 256)
        atomicAdd(&hist[dst[e] >> 8], 1);
    __syncthreads();
    for (int i = threadIdx.x; i < NB; i += 256)
        if (hist[i]) atomicAdd(&bucket_counts[i], hist[i]);
}

__global__ void k_bucketscan(const int* __restrict__ bucket_counts, int NB, int N, int E,
                             int* __restrict__ bucket_base, int* __restrict__ bucket_cursor,
                             int* __restrict__ rowptr) {
    __shared__ int sh[512];
    int t = threadIdx.x;
    int v = (t < NB) ? bucket_counts[t] : 0;
    sh[t] = v;
    __syncthreads();
    for (int off = 1; off < 512; off <<= 1) {
        int x = (t >= off) ? sh[t - off] : 0;
        __syncthreads();
        sh[t] += x;
        __syncthreads();
    }
    if (t < NB) {
        int b = sh[t] - v;
        bucket_base[t] = b;
        bucket_cursor[t] = b;
    }
    if (t == 0) { bucket_base[NB] = E; rowptr[N] = E; }
}

__global__ __launch_bounds__(256) void k_bin(const int* __restrict__ src,
                                             const int* __restrict__ dst, int E, int NB,
                                             int* __restrict__ bucket_cursor,
                                             unsigned int* __restrict__ binned) {
    __shared__ int hist[512];
    __shared__ int cur[512];
    for (int i = threadIdx.x; i < NB; i += 256) hist[i] = 0;
    __syncthreads();
    int base = blockIdx.x * BIN_CHUNK;
    int end = min(E, base + BIN_CHUNK);
    for (int e = base + threadIdx.x; e < end; e += 256)
        atomicAdd(&hist[dst[e] >> 8], 1);
    __syncthreads();
    for (int i = threadIdx.x; i < NB; i += 256)
        cur[i] = hist[i] ? atomicAdd(&bucket_cursor[i], hist[i]) : 0;
    __syncthreads();
    for (int e = base + threadIdx.x; e < end; e += 256) {
        int d = dst[e];
        int pos = atomicAdd(&cur[d >> 8], 1);
        binned[pos] = (unsigned int)src[e] | ((unsigned int)(d & 255) << 24);
    }
}

__global__ __launch_bounds__(256) void k_bucket(const unsigned int* __restrict__ binned,
                                                const int* __restrict__ bucket_base, int N,
                                                int* __restrict__ rowptr,
                                                float* __restrict__ dinv,
                                                int* __restrict__ csr_src) {
    __shared__ int cnt[256];
    __shared__ int sh[256];
    __shared__ int cur[256];
    int b = blockIdx.x;
    int t = threadIdx.x;
    int node0 = b << 8;
    int lo = bucket_base[b], hi = bucket_base[b + 1];
    cnt[t] = 0;
    __syncthreads();
    for (int p = lo + t; p < hi; p += 256)
        atomicAdd(&cnt[binned[p] >> 24], 1);
    __syncthreads();
    int v = cnt[t];
    sh[t] = v;
    __syncthreads();
    for (int off = 1; off < 256; off <<= 1) {
        int y = (t >= off) ? sh[t - off] : 0;
        __syncthreads();
        sh[t] += y;
        __syncthreads();
    }
    int gbase = lo + (sh[t] - v);
    int node = node0 + t;
    if (node < N) {
        rowptr[node] = gbase;
        dinv[node] = rsqrtf((float)v + 1.0f);   // deg = in-degree + self-loop
    }
    cur[t] = gbase;
    __syncthreads();
    for (int p = lo + t; p < hi; p += 256) {
        unsigned int pr = binned[p];
        int pos = atomicAdd(&cur[pr >> 24], 1);
        csr_src[pos] = (int)(pr & 0xFFFFFFu);
    }
}

// ---------------- BN stats reduce + params ----------------
// partial[b][t], t = (k<<4)|cg ; col j = cg*8+(k&7) ; stat = k>>3 (0=sum,1=sq)

__global__ __launch_bounds__(256) void k_statreduce(const float* __restrict__ partial,
                                                    int nblk, float* __restrict__ sp256) {
    int t = threadIdx.x;
    float acc = 0.f;
    for (int r = blockIdx.x; r < nblk; r += 32)
        acc += partial[(size_t)r * 256 + t];
    atomicAdd(&sp256[t], acc);
}

__global__ void k_bnparam(const float* __restrict__ sp256, const float* __restrict__ g,
                          const float* __restrict__ be, float* __restrict__ scale,
                          float* __restrict__ shift, float invN) {
    int j = threadIdx.x;  // 128 threads
    int cg = j >> 3, klo = j & 7;
    float s = sp256[(klo << 4) | cg];
    float q = sp256[((klo + 8) << 4) | cg];
    float m = s * invN;
    float var = q * invN - m * m;
    float r = rsqrtf(var + BN_EPS);
    float sc = g[j] * r;
    scale[j] = sc;
    shift[j] = be[j] - m * sc;
}

// ---------------- prep kernels ----------------

// W[128][M] fp32 -> BT[M][128] bf16 (transposed for MFMA B-frags)
__global__ void k_wprep(const float* __restrict__ W, ushort_t* __restrict__ BT, int M) {
    int col = blockIdx.x;
    int k = threadIdx.x;
    BT[col * 128 + k] = bf16rne(W[k * M + col]);
}

// x fp32 -> bf16, 8 elems/thread
__global__ __launch_bounds__(256) void k_xcvt(const float* __restrict__ X,
                                              ushort_t* __restrict__ Xb, int total8) {
    int i = blockIdx.x * 256 + threadIdx.x;
    if (i >= total8) return;
    float4 a = ((const float4*)X)[2 * i];
    float4 b = ((const float4*)X)[2 * i + 1];
    uint4 po;
    po.x = pack2(a.x, a.y); po.y = pack2(a.z, a.w);
    po.z = pack2(b.x, b.y); po.w = pack2(b.z, b.w);
    ((uint4*)Xb)[i] = po;
}

// bf16 in -> relu(in*scale+shift) [+ skip] -> bf16 out; 8 elems/thread
template<bool ADDSKIP>
__global__ __launch_bounds__(256) void k_bntrans(const ushort_t* __restrict__ Ain,
                                                 const float* __restrict__ scale,
                                                 const float* __restrict__ shift,
                                                 const ushort_t* __restrict__ skip,
                                                 ushort_t* __restrict__ Outb, int N) {
    int i = blockIdx.x * 256 + threadIdx.x;
    if (i >= N * 16) return;
    int j0 = (i & 15) * 8;
    uint4 raw = ((const uint4*)Ain)[i];
    float v[8];
    cvt2(raw.x, v[0], v[1]); cvt2(raw.y, v[2], v[3]);
    cvt2(raw.z, v[4], v[5]); cvt2(raw.w, v[6], v[7]);
    float4 sc0 = *(const float4*)&scale[j0];
    float4 sc1 = *(const float4*)&scale[j0 + 4];
    float4 sh0 = *(const float4*)&shift[j0];
    float4 sh1 = *(const float4*)&shift[j0 + 4];
    v[0] = fmaxf(v[0] * sc0.x + sh0.x, 0.f);
    v[1] = fmaxf(v[1] * sc0.y + sh0.y, 0.f);
    v[2] = fmaxf(v[2] * sc0.z + sh0.z, 0.f);
    v[3] = fmaxf(v[3] * sc0.w + sh0.w, 0.f);
    v[4] = fmaxf(v[4] * sc1.x + sh1.x, 0.f);
    v[5] = fmaxf(v[5] * sc1.y + sh1.y, 0.f);
    v[6] = fmaxf(v[6] * sc1.z + sh1.z, 0.f);
    v[7] = fmaxf(v[7] * sc1.w + sh1.w, 0.f);
    if constexpr (ADDSKIP) {
        uint4 s4 = ((const uint4*)skip)[i];
        float lo, hi;
        cvt2(s4.x, lo, hi); v[0] += lo; v[1] += hi;
        cvt2(s4.y, lo, hi); v[2] += lo; v[3] += hi;
        cvt2(s4.z, lo, hi); v[4] += lo; v[5] += hi;
        cvt2(s4.w, lo, hi); v[6] += lo; v[7] += hi;
    }
    uint4 po;
    po.x = pack2(v[0], v[1]); po.y = pack2(v[2], v[3]);
    po.z = pack2(v[4], v[5]); po.w = pack2(v[6], v[7]);
    ((uint4*)Outb)[i] = po;
}

// ---------------- MFMA GEMM: Out[N,M](bf16) = A[N,128](bf16) @ BT[M,128]^T ----------------
// mfma_f32_32x32x16_bf16; wave computes 32 rows x M cols; block = 4 waves = 128 rows.
// C/D: col=lane&31, row=(reg&3)+8*(reg>>2)+4*(lane>>5)  [m74/m101 verified]

template<int M>
__global__ __launch_bounds__(256) void k_mgemm(const ushort_t* __restrict__ A,
                                               const ushort_t* __restrict__ BT,
                                               ushort_t* __restrict__ Out, int N) {
    constexpr int CT = M / 32;   // col tiles per wave
    int wid = threadIdx.x >> 6;
    int lane = threadIdx.x & 63;
    int l31 = lane & 31;
    int khalf = (lane >> 5) * 8;
    int rowbase = blockIdx.x * 128 + wid * 32;
    int arow = rowbase + l31;

    f32x16 acc[CT] = {};

#pragma unroll
    for (int ks = 0; ks < 8; ++ks) {
        bf16x8 af = {};
        if (arow < N)
            af = as_bf16x8(*(const uint4*)&A[(size_t)arow * 128 + ks * 16 + khalf]);
#pragma unroll
        for (int ct = 0; ct < CT; ++ct) {
            int bcol = ct * 32 + l31;
            bf16x8 bfr = as_bf16x8(*(const uint4*)&BT[(size_t)bcol * 128 + ks * 16 + khalf]);
            acc[ct] = __builtin_amdgcn_mfma_f32_32x32x16_bf16(af, bfr, acc[ct], 0, 0, 0);
        }
    }

#pragma unroll
    for (int ct = 0; ct < CT; ++ct) {
        int col = ct * 32 + l31;
#pragma unroll
        for (int q = 0; q < 16; ++q) {
            int row = rowbase + (q & 3) + 8 * (q >> 2) + 4 * (lane >> 5);
            if (row < N)
                Out[(size_t)row * M + col] = bf16rne(acc[ct][q]);
        }
    }
}

// ---------------- Aggregation (bf16 gather, fp32 accumulate) ----------------
// out = (sum_e dinv[src_e]*h[src_e] + h[i]*di) * di + bias
// STATS: per-block partial stats written streaming (no device atomics).

template<int M, bool STATS, bool BF16OUT>
__global__ __launch_bounds__(256) void k_agg(const ushort_t* __restrict__ Hm,
                      const int* __restrict__ rowptr,
                      const int* __restrict__ csr_src, const float* __restrict__ dinv,
                      const float* __restrict__ bias, void* __restrict__ Out, int N,
                      float* __restrict__ partial) {
    constexpr int TPN = M / 8;           // threads per node
    constexpr int NPB = 256 / TPN;       // nodes per block
    int li = threadIdx.x / TPN;
    int lane = threadIdx.x % TPN;
    int i = blockIdx.x * NPB + li;
    bool valid = (i < N);
    int j0 = lane * 8;

    float o[8] = {0.f, 0.f, 0.f, 0.f, 0.f, 0.f, 0.f, 0.f};

    if (valid) {
        int p = rowptr[i], p1 = rowptr[i + 1];
        for (; p + 3 < p1; p += 4) {
            int s0 = csr_src[p + 0];
            int s1 = csr_src[p + 1];
            int s2 = csr_src[p + 2];
            int s3 = csr_src[p + 3];
            float c0 = dinv[s0], c1 = dinv[s1], c2 = dinv[s2], c3 = dinv[s3];
            uint4 g0 = *(const uint4*)&Hm[(size_t)s0 * M + j0];
            uint4 g1 = *(const uint4*)&Hm[(size_t)s1 * M + j0];
            uint4 g2 = *(const uint4*)&Hm[(size_t)s2 * M + j0];
            uint4 g3 = *(const uint4*)&Hm[(size_t)s3 * M + j0];
            float lo, hi;
            cvt2(g0.x, lo, hi); o[0] += lo * c0; o[1] += hi * c0;
            cvt2(g0.y, lo, hi); o[2] += lo * c0; o[3] += hi * c0;
            cvt2(g0.z, lo, hi); o[4] += lo * c0; o[5] += hi * c0;
            cvt2(g0.w, lo, hi); o[6] += lo * c0; o[7] += hi * c0;
            cvt2(g1.x, lo, hi); o[0] += lo * c1; o[1] += hi * c1;
            cvt2(g1.y, lo, hi); o[2] += lo * c1; o[3] += hi * c1;
            cvt2(g1.z, lo, hi); o[4] += lo * c1; o[5] += hi * c1;
            cvt2(g1.w, lo, hi); o[6] += lo * c1; o[7] += hi * c1;
            cvt2(g2.x, lo, hi); o[0] += lo * c2; o[1] += hi * c2;
            cvt2(g2.y, lo, hi); o[2] += lo * c2; o[3] += hi * c2;
            cvt2(g2.z, lo, hi); o[4] += lo * c2; o[5] += hi * c2;
            cvt2(g2.w, lo, hi); o[6] += lo * c2; o[7] += hi * c2;
            cvt2(g3.x, lo, hi); o[0] += lo * c3; o[1] += hi * c3;
            cvt2(g3.y, lo, hi); o[2] += lo * c3; o[3] += hi * c3;
            cvt2(g3.z, lo, hi); o[4] += lo * c3; o[5] += hi * c3;
            cvt2(g3.w, lo, hi); o[6] += lo * c3; o[7] += hi * c3;
        }
        for (; p < p1; ++p) {
            int s = csr_src[p];
            float cf = dinv[s];
            uint4 g = *(const uint4*)&Hm[(size_t)s * M + j0];
            float lo, hi;
            cvt2(g.x, lo, hi); o[0] += lo * cf; o[1] += hi * cf;
            cvt2(g.y, lo, hi); o[2] += lo * cf; o[3] += hi * cf;
            cvt2(g.z, lo, hi); o[4] += lo * cf; o[5] += hi * cf;
            cvt2(g.w, lo, hi); o[6] += lo * cf; o[7] += hi * cf;
        }

        float di = dinv[i];
        uint4 hs = *(const uint4*)&Hm[(size_t)i * M + j0];
        float lo, hi;
        cvt2(hs.x, lo, hi); o[0] += lo * di; o[1] += hi * di;
        cvt2(hs.y, lo, hi); o[2] += lo * di; o[3] += hi * di;
        cvt2(hs.z, lo, hi); o[4] += lo * di; o[5] += hi * di;
        cvt2(hs.w, lo, hi); o[6] += lo * di; o[7] += hi * di;

        float4 bv0 = *(const float4*)&bias[j0];
        float4 bv1 = *(const float4*)&bias[j0 + 4];
        o[0] = o[0] * di + bv0.x; o[1] = o[1] * di + bv0.y;
        o[2] = o[2] * di + bv0.z; o[3] = o[3] * di + bv0.w;
        o[4] = o[4] * di + bv1.x; o[5] = o[5] * di + bv1.y;
        o[6] = o[6] * di + bv1.z; o[7] = o[7] * di + bv1.w;
    }

    if constexpr (STATS) {
        float st[16];
#pragma unroll
        for (int k = 0; k < 8; ++k) { st[k] = o[k]; st[8 + k] = o[k] * o[k]; }
#pragma unroll
        for (int k = 0; k < 16; ++k) {
            st[k] += __shfl_xor(st[k], 16);
            st[k] += __shfl_xor(st[k], 32);
        }
        __shared__ float red[4][16][16];
        int wv = threadIdx.x >> 6;
        int ln = threadIdx.x & 63;
        if (ln < 16) {
#pragma unroll
            for (int k = 0; k < 16; ++k) red[wv][ln][k] = st[k];
        }
        __syncthreads();
        {
            int t = threadIdx.x;
            int cg = t & 15, k = t >> 4;
            float s = red[0][cg][k] + red[1][cg][k] + red[2][cg][k] + red[3][cg][k];
            partial[(size_t)blockIdx.x * 256 + t] = s;   // coalesced full-line write
        }
    }

    if constexpr (BF16OUT) {
        if (valid) {
            uint4 po;
            po.x = pack2(o[0], o[1]); po.y = pack2(o[2], o[3]);
            po.z = pack2(o[4], o[5]); po.w = pack2(o[6], o[7]);
            *(uint4*)&((ushort_t*)Out)[(size_t)i * M + j0] = po;
        }
    } else {
        __shared__ float outs[NPB][M + 4];
#pragma unroll
        for (int cc = 0; cc < 8; ++cc) outs[li][lane * 8 + cc] = o[cc];
        __syncthreads();
        float* Of = (float*)Out;
        int i0 = blockIdx.x * NPB;
        constexpr int Q = M / 4;
        for (int f = threadIdx.x; f < NPB * Q; f += 256) {
            int node = f / Q;
            int q = f % Q;
            if (i0 + node < N)
                *(float4*)&Of[(size_t)(i0 + node) * M + q * 4] = *(float4*)&outs[node][q * 4];
        }
    }
}

// ---------------- launch ----------------

extern "C" void kernel_launch(void* const* d_in, const int* in_sizes, int n_in,
                              void* d_out, int out_size, void* d_ws, size_t ws_size,
                              hipStream_t stream) {
    const float* x   = (const float*)d_in[0];
    const int*   ei  = (const int*)d_in[1];
    const float* W1  = (const float*)d_in[2];
    const float* b1  = (const float*)d_in[3];
    const float* g1  = (const float*)d_in[4];
    const float* be1 = (const float*)d_in[5];
    const float* W2  = (const float*)d_in[6];
    const float* b2  = (const float*)d_in[7];
    const float* g2  = (const float*)d_in[8];
    const float* be2 = (const float*)d_in[9];
    const float* W3  = (const float*)d_in[10];
    const float* b3  = (const float*)d_in[11];

    int N = in_sizes[0] / 128;
    int E = in_sizes[1] / 2;
    const int* srcp = ei;
    const int* dstp = ei + E;
    int NB = (N + 255) >> 8;

    char* ws = (char*)d_ws;
    size_t off = 0;
    auto alloc = [&](size_t bytes) {
        void* p = ws + off;
        off += (bytes + 255) & ~(size_t)255;
        return p;
    };

    int nblk128 = (N + 15) / 16;   // k_agg<128> grid (STATS partial rows)

    int*   rowptr   = (int*)alloc(((size_t)N + 1) * 4);
    int*   csr_src  = (int*)alloc((size_t)E * 4);
    float* dinv     = (float*)alloc((size_t)N * 4);
    int*   bucket_counts = (int*)alloc(512 * 4);
    int*   bucket_base   = (int*)alloc(513 * 4);
    int*   bucket_cursor = (int*)alloc(512 * 4);
    float* partialA = (float*)alloc((size_t)nblk128 * 256 * 4);
    float* partialB = (float*)alloc((size_t)nblk128 * 256 * 4);
    float* sp256A   = (float*)alloc(256 * 4);
    float* sp256B   = (float*)alloc(256 * 4);
    float* scale1   = (float*)alloc(128 * 4);
    float* shift1   = (float*)alloc(128 * 4);
    float* scale2   = (float*)alloc(128 * 4);
    float* shift2   = (float*)alloc(128 * 4);
    ushort_t* BT1   = (ushort_t*)alloc(128 * 128 * 2);
    ushort_t* BT2   = (ushort_t*)alloc(128 * 128 * 2);
    ushort_t* BT3   = (ushort_t*)alloc(64 * 128 * 2);
    ushort_t* xbf   = (ushort_t*)alloc((size_t)N * 128 * 2);  // bf16 x
    ushort_t* hbuf  = (ushort_t*)alloc((size_t)N * 128 * 2);  // bf16 h-table
    ushort_t* x1bf  = (ushort_t*)alloc((size_t)N * 128 * 2);  // bf16 x1 (skip + gemm2 A)
    ushort_t* x2bf  = (ushort_t*)alloc((size_t)N * 128 * 2);  // bf16 x2 (gemm3 A)
    ushort_t* abuf1 = (ushort_t*)alloc((size_t)N * 128 * 2);  // bf16 a1
    ushort_t* abuf2 = (ushort_t*)alloc((size_t)N * 128 * 2);  // bf16 a2
    unsigned int* binned = (unsigned int*)abuf1;  // alias: dead before abuf1 written

    float invN = 1.0f / (float)N;
    int nbE = (E + BIN_CHUNK - 1) / BIN_CHUNK;
    int gemmBlocks = (N + 127) / 128;
    int ncvt8 = N * 16;

    // CSR build (2-pass counting sort, packed binned)
    hipMemsetAsync(bucket_counts, 0, 512 * 4, stream);
    k_binhist<<<nbE, 256, 0, stream>>>(dstp, E, NB, bucket_counts);
    k_bucketscan<<<1, 512, 0, stream>>>(bucket_counts, NB, N, E,
                                        bucket_base, bucket_cursor, rowptr);
    k_bin<<<nbE, 256, 0, stream>>>(srcp, dstp, E, NB, bucket_cursor, binned);
    k_bucket<<<NB, 256, 0, stream>>>(binned, bucket_base, N, rowptr, dinv, csr_src);
    hipMemsetAsync(sp256A, 0, 256 * 4, stream);
    hipMemsetAsync(sp256B, 0, 256 * 4, stream);

    // preps: W transposes + x -> bf16
    k_wprep<<<128, 128, 0, stream>>>(W1, BT1, 128);
    k_wprep<<<128, 128, 0, stream>>>(W2, BT2, 128);
    k_wprep<<<64, 128, 0, stream>>>(W3, BT3, 64);
    k_xcvt<<<(ncvt8 + 255) / 256, 256, 0, stream>>>(x, xbf, ncvt8);

    // layer 1: h = x@W1 ; a1 = agg(h) + partial stats (bf16)
    k_mgemm<128><<<gemmBlocks, 256, 0, stream>>>(xbf, BT1, hbuf, N);
    k_agg<128, true, true><<<nblk128, 256, 0, stream>>>(hbuf, rowptr, csr_src, dinv,
                                                        b1, abuf1, N, partialA);
    k_statreduce<<<32, 256, 0, stream>>>(partialA, nblk128, sp256A);
    k_bnparam<<<1, 128, 0, stream>>>(sp256A, g1, be1, scale1, shift1, invN);

    // layer 2: x1 = relu(bn1(a1)) ; h = x1@W2 ; a2 = agg(h) + partial stats
    k_bntrans<false><<<(ncvt8 + 255) / 256, 256, 0, stream>>>(abuf1, scale1, shift1,
                                                              nullptr, x1bf, N);
    k_mgemm<128><<<gemmBlocks, 256, 0, stream>>>(x1bf, BT2, hbuf, N);
    k_agg<128, true, true><<<nblk128, 256, 0, stream>>>(hbuf, rowptr, csr_src, dinv,
                                                        b2, abuf2, N, partialB);
    k_statreduce<<<32, 256, 0, stream>>>(partialB, nblk128, sp256B);
    k_bnparam<<<1, 128, 0, stream>>>(sp256B, g2, be2, scale2, shift2, invN);

    // layer 3: x2 = relu(bn2(a2)) + x1 ; h = x2@W3 ; out = agg(h) (fp32)
    k_bntrans<true><<<(ncvt8 + 255) / 256, 256, 0, stream>>>(abuf2, scale2, shift2,
                                                             x1bf, x2bf, N);
    k_mgemm<64><<<gemmBlocks, 256, 0, stream>>>(x2bf, BT3, hbuf, N);
    k_agg<64, false, false><<<(N + 31) / 32, 256, 0, stream>>>(hbuf, rowptr, csr_src, dinv,
                                                               b3, d_out, N, nullptr);
}

// Round 12
// 373.686 us; speedup vs baseline: 1.2481x; 1.2481x over previous
//
#include <hip/hip_runtime.h>

#define BN_EPS 1e-5f

typedef unsigned short ushort_t;
typedef __attribute__((ext_vector_type(8))) short bf16x8;
typedef __attribute__((ext_vector_type(16))) float f32x16;

// round-to-nearest-even fp32 -> bf16 (finite inputs)
__device__ __forceinline__ ushort_t bf16rne(float f) {
    unsigned int u = __float_as_uint(f);
    unsigned int r = (u + 0x7FFFu + ((u >> 16) & 1u)) >> 16;
    return (ushort_t)r;
}
__device__ __forceinline__ unsigned int pack2(float a, float b) {
    return (unsigned int)bf16rne(a) | ((unsigned int)bf16rne(b) << 16);
}
__device__ __forceinline__ void cvt2(unsigned int u, float& lo, float& hi) {
    lo = __uint_as_float(u << 16);
    hi = __uint_as_float(u & 0xFFFF0000u);
}
__device__ __forceinline__ bf16x8 as_bf16x8(uint4 u) {
    union { uint4 u; bf16x8 v; } c; c.u = u; return c.v;
}

// ---------------- CSR build: locality-aware 2-pass counting sort ----------------
// binned entry packs src (bits 0-23) | local-dst (bits 24-31).

#define BIN_CHUNK 4096

__global__ __launch_bounds__(256) void k_binhist(const int* __restrict__ dst, int E, int NB,
                                                 int* __restrict__ bucket_counts) {
    __shared__ int hist[512];
    for (int i = threadIdx.x; i < NB; i += 256) hist[i] = 0;
    __syncthreads();
    int base = blockIdx.x * BIN_CHUNK;
    int end = min(E, base + BIN_CHUNK);
    for (int e = base + threadIdx.x; e < end; e += 256)
        atomicAdd(&hist[dst[e] >> 8], 1);
    __syncthreads();
    for (int i = threadIdx.x; i < NB; i += 256)
        if (hist[i]) atomicAdd(&bucket_counts[i], hist[i]);
}

__global__ void k_bucketscan(const int* __restrict__ bucket_counts, int NB, int N, int E,
                             int* __restrict__ bucket_base, int* __restrict__ bucket_cursor,
                             int* __restrict__ rowptr) {
    __shared__ int sh[512];
    int t = threadIdx.x;
    int v = (t < NB) ? bucket_counts[t] : 0;
    sh[t] = v;
    __syncthreads();
    for (int off = 1; off < 512; off <<= 1) {
        int x = (t >= off) ? sh[t - off] : 0;
        __syncthreads();
        sh[t] += x;
        __syncthreads();
    }
    if (t < NB) {
        int b = sh[t] - v;
        bucket_base[t] = b;
        bucket_cursor[t] = b;
    }
    if (t == 0) { bucket_base[NB] = E; rowptr[N] = E; }
}

__global__ __launch_bounds__(256) void k_bin(const int* __restrict__ src,
                                             const int* __restrict__ dst, int E, int NB,
                                             int* __restrict__ bucket_cursor,
                                             unsigned int* __restrict__ binned) {
    __shared__ int hist[512];
    __shared__ int cur[512];
    for (int i = threadIdx.x; i < NB; i += 256) hist[i] = 0;
    __syncthreads();
    int base = blockIdx.x * BIN_CHUNK;
    int end = min(E, base + BIN_CHUNK);
    for (int e = base + threadIdx.x; e < end; e += 256)
        atomicAdd(&hist[dst[e] >> 8], 1);
    __syncthreads();
    for (int i = threadIdx.x; i < NB; i += 256)
        cur[i] = hist[i] ? atomicAdd(&bucket_cursor[i], hist[i]) : 0;
    __syncthreads();
    for (int e = base + threadIdx.x; e < end; e += 256) {
        int d = dst[e];
        int pos = atomicAdd(&cur[d >> 8], 1);
        binned[pos] = (unsigned int)src[e] | ((unsigned int)(d & 255) << 24);
    }
}

__global__ __launch_bounds__(256) void k_bucket(const unsigned int* __restrict__ binned,
                                                const int* __restrict__ bucket_base, int N,
                                                int* __restrict__ rowptr,
                                                float* __restrict__ dinv,
                                                int* __restrict__ csr_src) {
    __shared__ int cnt[256];
    __shared__ int sh[256];
    __shared__ int cur[256];
    int b = blockIdx.x;
    int t = threadIdx.x;
    int node0 = b << 8;
    int lo = bucket_base[b], hi = bucket_base[b + 1];
    cnt[t] = 0;
    __syncthreads();
    for (int p = lo + t; p < hi; p += 256)
        atomicAdd(&cnt[binned[p] >> 24], 1);
    __syncthreads();
    int v = cnt[t];
    sh[t] = v;
    __syncthreads();
    for (int off = 1; off < 256; off <<= 1) {
        int y = (t >= off) ? sh[t - off] : 0;
        __syncthreads();
        sh[t] += y;
        __syncthreads();
    }
    int gbase = lo + (sh[t] - v);
    int node = node0 + t;
    if (node < N) {
        rowptr[node] = gbase;
        dinv[node] = rsqrtf((float)v + 1.0f);   // deg = in-degree + self-loop
    }
    cur[t] = gbase;
    __syncthreads();
    for (int p = lo + t; p < hi; p += 256) {
        unsigned int pr = binned[p];
        int pos = atomicAdd(&cur[pr >> 24], 1);
        csr_src[pos] = (int)(pr & 0xFFFFFFu);
    }
}

// ---------------- BN stats reduce + params ----------------
// partial[b][t], t = (k<<4)|cg ; col j = cg*8+(k&7) ; stat = k>>3 (0=sum,1=sq)

__global__ __launch_bounds__(256) void k_statreduce(const float* __restrict__ partial,
                                                    int nblk, float* __restrict__ sp256) {
    int t = threadIdx.x;
    float acc = 0.f;
    for (int r = blockIdx.x; r < nblk; r += gridDim.x)
        acc += partial[(size_t)r * 256 + t];
    atomicAdd(&sp256[t], acc);
}

__global__ void k_bnparam(const float* __restrict__ sp256, const float* __restrict__ g,
                          const float* __restrict__ be, float* __restrict__ scale,
                          float* __restrict__ shift, float invN) {
    int j = threadIdx.x;  // 128 threads
    int cg = j >> 3, klo = j & 7;
    float s = sp256[(klo << 4) | cg];
    float q = sp256[((klo + 8) << 4) | cg];
    float m = s * invN;
    float var = q * invN - m * m;
    float r = rsqrtf(var + BN_EPS);
    float sc = g[j] * r;
    scale[j] = sc;
    shift[j] = be[j] - m * sc;
}

// ---------------- prep kernels ----------------

// W[128][M] fp32 -> BT[M][128] bf16 (transposed for MFMA B-frags)
__global__ void k_wprep(const float* __restrict__ W, ushort_t* __restrict__ BT, int M) {
    int col = blockIdx.x;
    int k = threadIdx.x;
    BT[col * 128 + k] = bf16rne(W[k * M + col]);
}

// x fp32 -> bf16, 8 elems/thread
__global__ __launch_bounds__(256) void k_xcvt(const float* __restrict__ X,
                                              ushort_t* __restrict__ Xb, int total8) {
    int i = blockIdx.x * 256 + threadIdx.x;
    if (i >= total8) return;
    float4 a = ((const float4*)X)[2 * i];
    float4 b = ((const float4*)X)[2 * i + 1];
    uint4 po;
    po.x = pack2(a.x, a.y); po.y = pack2(a.z, a.w);
    po.z = pack2(b.x, b.y); po.w = pack2(b.z, b.w);
    ((uint4*)Xb)[i] = po;
}

// bf16 in -> relu(in*scale+shift) [+ skip] -> bf16 out; 8 elems/thread
template<bool ADDSKIP>
__global__ __launch_bounds__(256) void k_bntrans(const ushort_t* __restrict__ Ain,
                                                 const float* __restrict__ scale,
                                                 const float* __restrict__ shift,
                                                 const ushort_t* __restrict__ skip,
                                                 ushort_t* __restrict__ Outb, int N) {
    int i = blockIdx.x * 256 + threadIdx.x;
    if (i >= N * 16) return;
    int j0 = (i & 15) * 8;
    uint4 raw = ((const uint4*)Ain)[i];
    float v[8];
    cvt2(raw.x, v[0], v[1]); cvt2(raw.y, v[2], v[3]);
    cvt2(raw.z, v[4], v[5]); cvt2(raw.w, v[6], v[7]);
    float4 sc0 = *(const float4*)&scale[j0];
    float4 sc1 = *(const float4*)&scale[j0 + 4];
    float4 sh0 = *(const float4*)&shift[j0];
    float4 sh1 = *(const float4*)&shift[j0 + 4];
    v[0] = fmaxf(v[0] * sc0.x + sh0.x, 0.f);
    v[1] = fmaxf(v[1] * sc0.y + sh0.y, 0.f);
    v[2] = fmaxf(v[2] * sc0.z + sh0.z, 0.f);
    v[3] = fmaxf(v[3] * sc0.w + sh0.w, 0.f);
    v[4] = fmaxf(v[4] * sc1.x + sh1.x, 0.f);
    v[5] = fmaxf(v[5] * sc1.y + sh1.y, 0.f);
    v[6] = fmaxf(v[6] * sc1.z + sh1.z, 0.f);
    v[7] = fmaxf(v[7] * sc1.w + sh1.w, 0.f);
    if constexpr (ADDSKIP) {
        uint4 s4 = ((const uint4*)skip)[i];
        float lo, hi;
        cvt2(s4.x, lo, hi); v[0] += lo; v[1] += hi;
        cvt2(s4.y, lo, hi); v[2] += lo; v[3] += hi;
        cvt2(s4.z, lo, hi); v[4] += lo; v[5] += hi;
        cvt2(s4.w, lo, hi); v[6] += lo; v[7] += hi;
    }
    uint4 po;
    po.x = pack2(v[0], v[1]); po.y = pack2(v[2], v[3]);
    po.z = pack2(v[4], v[5]); po.w = pack2(v[6], v[7]);
    ((uint4*)Outb)[i] = po;
}

// ---------------- MFMA GEMM: Out[N,M](bf16) = A[N,128](bf16) @ BT[M,128]^T ----------------
// mfma_f32_32x32x16_bf16; wave computes 32 rows x M cols; block = 4 waves = 128 rows.
// C/D: col=lane&31, row=(reg&3)+8*(reg>>2)+4*(lane>>5)  [m74/m101 verified]

template<int M>
__global__ __launch_bounds__(256) void k_mgemm(const ushort_t* __restrict__ A,
                                               const ushort_t* __restrict__ BT,
                                               ushort_t* __restrict__ Out, int N) {
    constexpr int CT = M / 32;   // col tiles per wave
    int wid = threadIdx.x >> 6;
    int lane = threadIdx.x & 63;
    int l31 = lane & 31;
    int khalf = (lane >> 5) * 8;
    int rowbase = blockIdx.x * 128 + wid * 32;
    int arow = rowbase + l31;

    f32x16 acc[CT] = {};

#pragma unroll
    for (int ks = 0; ks < 8; ++ks) {
        bf16x8 af = {};
        if (arow < N)
            af = as_bf16x8(*(const uint4*)&A[(size_t)arow * 128 + ks * 16 + khalf]);
#pragma unroll
        for (int ct = 0; ct < CT; ++ct) {
            int bcol = ct * 32 + l31;
            bf16x8 bfr = as_bf16x8(*(const uint4*)&BT[(size_t)bcol * 128 + ks * 16 + khalf]);
            acc[ct] = __builtin_amdgcn_mfma_f32_32x32x16_bf16(af, bfr, acc[ct], 0, 0, 0);
        }
    }

#pragma unroll
    for (int ct = 0; ct < CT; ++ct) {
        int col = ct * 32 + l31;
#pragma unroll
        for (int q = 0; q < 16; ++q) {
            int row = rowbase + (q & 3) + 8 * (q >> 2) + 4 * (lane >> 5);
            if (row < N)
                Out[(size_t)row * M + col] = bf16rne(acc[ct][q]);
        }
    }
}

// ---------------- Aggregation (bf16 gather, fp32 accumulate) ----------------
// out = (sum_e dinv[src_e]*h[src_e] + h[i]*di) * di + bias
// STATS: per-block partial stats written streaming (no device atomics).

template<int M, bool STATS, bool BF16OUT>
__global__ __launch_bounds__(256) void k_agg(const ushort_t* __restrict__ Hm,
                      const int* __restrict__ rowptr,
                      const int* __restrict__ csr_src, const float* __restrict__ dinv,
                      const float* __restrict__ bias, void* __restrict__ Out, int N,
                      float* __restrict__ partial) {
    constexpr int TPN = M / 8;           // threads per node
    constexpr int NPB = 256 / TPN;       // nodes per block
    int li = threadIdx.x / TPN;
    int lane = threadIdx.x % TPN;
    int i = blockIdx.x * NPB + li;
    bool valid = (i < N);
    int j0 = lane * 8;

    float o[8] = {0.f, 0.f, 0.f, 0.f, 0.f, 0.f, 0.f, 0.f};

    if (valid) {
        int p = rowptr[i], p1 = rowptr[i + 1];
        for (; p + 3 < p1; p += 4) {
            int s0 = csr_src[p + 0];
            int s1 = csr_src[p + 1];
            int s2 = csr_src[p + 2];
            int s3 = csr_src[p + 3];
            float c0 = dinv[s0], c1 = dinv[s1], c2 = dinv[s2], c3 = dinv[s3];
            uint4 g0 = *(const uint4*)&Hm[(size_t)s0 * M + j0];
            uint4 g1 = *(const uint4*)&Hm[(size_t)s1 * M + j0];
            uint4 g2 = *(const uint4*)&Hm[(size_t)s2 * M + j0];
            uint4 g3 = *(const uint4*)&Hm[(size_t)s3 * M + j0];
            float lo, hi;
            cvt2(g0.x, lo, hi); o[0] += lo * c0; o[1] += hi * c0;
            cvt2(g0.y, lo, hi); o[2] += lo * c0; o[3] += hi * c0;
            cvt2(g0.z, lo, hi); o[4] += lo * c0; o[5] += hi * c0;
            cvt2(g0.w, lo, hi); o[6] += lo * c0; o[7] += hi * c0;
            cvt2(g1.x, lo, hi); o[0] += lo * c1; o[1] += hi * c1;
            cvt2(g1.y, lo, hi); o[2] += lo * c1; o[3] += hi * c1;
            cvt2(g1.z, lo, hi); o[4] += lo * c1; o[5] += hi * c1;
            cvt2(g1.w, lo, hi); o[6] += lo * c1; o[7] += hi * c1;
            cvt2(g2.x, lo, hi); o[0] += lo * c2; o[1] += hi * c2;
            cvt2(g2.y, lo, hi); o[2] += lo * c2; o[3] += hi * c2;
            cvt2(g2.z, lo, hi); o[4] += lo * c2; o[5] += hi * c2;
            cvt2(g2.w, lo, hi); o[6] += lo * c2; o[7] += hi * c2;
            cvt2(g3.x, lo, hi); o[0] += lo * c3; o[1] += hi * c3;
            cvt2(g3.y, lo, hi); o[2] += lo * c3; o[3] += hi * c3;
            cvt2(g3.z, lo, hi); o[4] += lo * c3; o[5] += hi * c3;
            cvt2(g3.w, lo, hi); o[6] += lo * c3; o[7] += hi * c3;
        }
        for (; p < p1; ++p) {
            int s = csr_src[p];
            float cf = dinv[s];
            uint4 g = *(const uint4*)&Hm[(size_t)s * M + j0];
            float lo, hi;
            cvt2(g.x, lo, hi); o[0] += lo * cf; o[1] += hi * cf;
            cvt2(g.y, lo, hi); o[2] += lo * cf; o[3] += hi * cf;
            cvt2(g.z, lo, hi); o[4] += lo * cf; o[5] += hi * cf;
            cvt2(g.w, lo, hi); o[6] += lo * cf; o[7] += hi * cf;
        }

        float di = dinv[i];
        uint4 hs = *(const uint4*)&Hm[(size_t)i * M + j0];
        float lo, hi;
        cvt2(hs.x, lo, hi); o[0] += lo * di; o[1] += hi * di;
        cvt2(hs.y, lo, hi); o[2] += lo * di; o[3] += hi * di;
        cvt2(hs.z, lo, hi); o[4] += lo * di; o[5] += hi * di;
        cvt2(hs.w, lo, hi); o[6] += lo * di; o[7] += hi * di;

        float4 bv0 = *(const float4*)&bias[j0];
        float4 bv1 = *(const float4*)&bias[j0 + 4];
        o[0] = o[0] * di + bv0.x; o[1] = o[1] * di + bv0.y;
        o[2] = o[2] * di + bv0.z; o[3] = o[3] * di + bv0.w;
        o[4] = o[4] * di + bv1.x; o[5] = o[5] * di + bv1.y;
        o[6] = o[6] * di + bv1.z; o[7] = o[7] * di + bv1.w;
    }

    if constexpr (STATS) {
        float st[16];
#pragma unroll
        for (int k = 0; k < 8; ++k) { st[k] = o[k]; st[8 + k] = o[k] * o[k]; }
#pragma unroll
        for (int k = 0; k < 16; ++k) {
            st[k] += __shfl_xor(st[k], 16);
            st[k] += __shfl_xor(st[k], 32);
        }
        __shared__ float red[4][16][16];
        int wv = threadIdx.x >> 6;
        int ln = threadIdx.x & 63;
        if (ln < 16) {
#pragma unroll
            for (int k = 0; k < 16; ++k) red[wv][ln][k] = st[k];
        }
        __syncthreads();
        {
            int t = threadIdx.x;
            int cg = t & 15, k = t >> 4;
            float s = red[0][cg][k] + red[1][cg][k] + red[2][cg][k] + red[3][cg][k];
            partial[(size_t)blockIdx.x * 256 + t] = s;   // coalesced full-line write
        }
    }

    if constexpr (BF16OUT) {
        if (valid) {
            uint4 po;
            po.x = pack2(o[0], o[1]); po.y = pack2(o[2], o[3]);
            po.z = pack2(o[4], o[5]); po.w = pack2(o[6], o[7]);
            *(uint4*)&((ushort_t*)Out)[(size_t)i * M + j0] = po;
        }
    } else {
        __shared__ float outs[NPB][M + 4];
#pragma unroll
        for (int cc = 0; cc < 8; ++cc) outs[li][lane * 8 + cc] = o[cc];
        __syncthreads();
        float* Of = (float*)Out;
        int i0 = blockIdx.x * NPB;
        constexpr int Q = M / 4;
        for (int f = threadIdx.x; f < NPB * Q; f += 256) {
            int node = f / Q;
            int q = f % Q;
            if (i0 + node < N)
                *(float4*)&Of[(size_t)(i0 + node) * M + q * 4] = *(float4*)&outs[node][q * 4];
        }
    }
}

// ---------------- launch ----------------

extern "C" void kernel_launch(void* const* d_in, const int* in_sizes, int n_in,
                              void* d_out, int out_size, void* d_ws, size_t ws_size,
                              hipStream_t stream) {
    const float* x   = (const float*)d_in[0];
    const int*   ei  = (const int*)d_in[1];
    const float* W1  = (const float*)d_in[2];
    const float* b1  = (const float*)d_in[3];
    const float* g1  = (const float*)d_in[4];
    const float* be1 = (const float*)d_in[5];
    const float* W2  = (const float*)d_in[6];
    const float* b2  = (const float*)d_in[7];
    const float* g2  = (const float*)d_in[8];
    const float* be2 = (const float*)d_in[9];
    const float* W3  = (const float*)d_in[10];
    const float* b3  = (const float*)d_in[11];

    int N = in_sizes[0] / 128;
    int E = in_sizes[1] / 2;
    const int* srcp = ei;
    const int* dstp = ei + E;
    int NB = (N + 255) >> 8;

    char* ws = (char*)d_ws;
    size_t off = 0;
    auto alloc = [&](size_t bytes) {
        void* p = ws + off;
        off += (bytes + 255) & ~(size_t)255;
        return p;
    };

    int nblk128 = (N + 15) / 16;   // k_agg<128> grid (STATS partial rows)

    int*   rowptr   = (int*)alloc(((size_t)N + 1) * 4);
    int*   csr_src  = (int*)alloc((size_t)E * 4);
    float* dinv     = (float*)alloc((size_t)N * 4);
    int*   bucket_counts = (int*)alloc(512 * 4);
    int*   bucket_base   = (int*)alloc(513 * 4);
    int*   bucket_cursor = (int*)alloc(512 * 4);
    float* partialA = (float*)alloc((size_t)nblk128 * 256 * 4);
    float* partialB = (float*)alloc((size_t)nblk128 * 256 * 4);
    float* sp256A   = (float*)alloc(256 * 4);
    float* sp256B   = (float*)alloc(256 * 4);
    float* scale1   = (float*)alloc(128 * 4);
    float* shift1   = (float*)alloc(128 * 4);
    float* scale2   = (float*)alloc(128 * 4);
    float* shift2   = (float*)alloc(128 * 4);
    ushort_t* BT1   = (ushort_t*)alloc(128 * 128 * 2);
    ushort_t* BT2   = (ushort_t*)alloc(128 * 128 * 2);
    ushort_t* BT3   = (ushort_t*)alloc(64 * 128 * 2);
    ushort_t* xbf   = (ushort_t*)alloc((size_t)N * 128 * 2);  // bf16 x
    ushort_t* hbuf  = (ushort_t*)alloc((size_t)N * 128 * 2);  // bf16 h-table
    ushort_t* x1bf  = (ushort_t*)alloc((size_t)N * 128 * 2);  // bf16 x1 (skip + gemm2 A)
    ushort_t* x2bf  = (ushort_t*)alloc((size_t)N * 128 * 2);  // bf16 x2 (gemm3 A)
    ushort_t* abuf1 = (ushort_t*)alloc((size_t)N * 128 * 2);  // bf16 a1
    ushort_t* abuf2 = (ushort_t*)alloc((size_t)N * 128 * 2);  // bf16 a2
    unsigned int* binned = (unsigned int*)abuf1;  // alias: dead before abuf1 written

    float invN = 1.0f / (float)N;
    int nbE = (E + BIN_CHUNK - 1) / BIN_CHUNK;
    int gemmBlocks = (N + 127) / 128;
    int ncvt8 = N * 16;

    // CSR build (2-pass counting sort, packed binned)
    hipMemsetAsync(bucket_counts, 0, 512 * 4, stream);
    k_binhist<<<nbE, 256, 0, stream>>>(dstp, E, NB, bucket_counts);
    k_bucketscan<<<1, 512, 0, stream>>>(bucket_counts, NB, N, E,
                                        bucket_base, bucket_cursor, rowptr);
    k_bin<<<nbE, 256, 0, stream>>>(srcp, dstp, E, NB, bucket_cursor, binned);
    k_bucket<<<NB, 256, 0, stream>>>(binned, bucket_base, N, rowptr, dinv, csr_src);
    hipMemsetAsync(sp256A, 0, 256 * 4, stream);
    hipMemsetAsync(sp256B, 0, 256 * 4, stream);

    // preps: W transposes + x -> bf16
    k_wprep<<<128, 128, 0, stream>>>(W1, BT1, 128);
    k_wprep<<<128, 128, 0, stream>>>(W2, BT2, 128);
    k_wprep<<<64, 128, 0, stream>>>(W3, BT3, 64);
    k_xcvt<<<(ncvt8 + 255) / 256, 256, 0, stream>>>(x, xbf, ncvt8);

    // layer 1: h = x@W1 ; a1 = agg(h) + partial stats (bf16)
    k_mgemm<128><<<gemmBlocks, 256, 0, stream>>>(xbf, BT1, hbuf, N);
    k_agg<128, true, true><<<nblk128, 256, 0, stream>>>(hbuf, rowptr, csr_src, dinv,
                                                        b1, abuf1, N, partialA);
    k_statreduce<<<256, 256, 0, stream>>>(partialA, nblk128, sp256A);
    k_bnparam<<<1, 128, 0, stream>>>(sp256A, g1, be1, scale1, shift1, invN);

    // layer 2: x1 = relu(bn1(a1)) ; h = x1@W2 ; a2 = agg(h) + partial stats
    k_bntrans<false><<<(ncvt8 + 255) / 256, 256, 0, stream>>>(abuf1, scale1, shift1,
                                                              nullptr, x1bf, N);
    k_mgemm<128><<<gemmBlocks, 256, 0, stream>>>(x1bf, BT2, hbuf, N);
    k_agg<128, true, true><<<nblk128, 256, 0, stream>>>(hbuf, rowptr, csr_src, dinv,
                                                        b2, abuf2, N, partialB);
    k_statreduce<<<256, 256, 0, stream>>>(partialB, nblk128, sp256B);
    k_bnparam<<<1, 128, 0, stream>>>(sp256B, g2, be2, scale2, shift2, invN);

    // layer 3: x2 = relu(bn2(a2)) + x1 ; h = x2@W3 ; out = agg(h) (fp32)
    k_bntrans<true><<<(ncvt8 + 255) / 256, 256, 0, stream>>>(abuf2, scale2, shift2,
                                                             x1bf, x2bf, N);
    k_mgemm<64><<<gemmBlocks, 256, 0, stream>>>(x2bf, BT3, hbuf, N);
    k_agg<64, false, false><<<(N + 31) / 32, 256, 0, stream>>>(hbuf, rowptr, csr_src, dinv,
                                                               b3, d_out, N, nullptr);
}